// Round 11
// baseline (1382.052 us; speedup 1.0000x reference)
//
#include <hip/hip_runtime.h>
#include <hip/hip_bf16.h>

#define NH_N 50000
#define NV_N 100000
#define NE_N 150000
#define E_N  300000
#define HD   128
#define NLAY 3
#define NBAT 256
#define NSCA 22
#define PS   8   // pool row splits

// proj grid split (64-row tiles)
#define NBH 782    // ceil(50000/64)
#define NBV 1563   // ceil(100000/64)
#define NBE 2344   // ceil(150000/64)

// gather grid: 32 rows/block
#define GB_HV 3125   // NV/32
#define GB_EV 3125
#define GB_VH 1563   // ceil(50000/32)
#define GB_VE 4688   // ceil(150000/32)
#define GB_TOT (GB_HV + GB_EV + GB_VH + GB_VE)  // 12501

// gemm grid: 64-row tiles, 2 col-halves, 4 tiles/block
#define TV 1563
#define TH 782
#define TE 2344
#define TPB 4
#define BV 391   // ceil(1563/4)
#define BH 196   // ceil(782/4)
#define BE 586   // ceil(2344/4)
#define GEMM_BLOCKS (2*(BV+BH+BE))   // 2346
#define GEMM_LDS (3*32768 + 16384)   // 114688

typedef unsigned short u16;
typedef __attribute__((ext_vector_type(8))) short short8v;
typedef __attribute__((ext_vector_type(4))) float f32x4;

__device__ inline u16 f2bf(float f) { __hip_bfloat16 h = __float2bfloat16(f); return *(u16*)&h; }
__device__ inline float bf2f(u16 u) { __hip_bfloat16 h; *(u16*)&h = u; return __bfloat162float(h); }

__device__ inline int lower_bound_i(const int* __restrict__ a, int n, int v) {
  int lo = 0, hi = n;
  while (lo < hi) { int m = (lo + hi) >> 1; if (a[m] < v) lo = m + 1; else hi = m; }
  return lo;
}

// ---------------- zero fill ----------------
__global__ void zero_kernel(int* __restrict__ p, int n) {
  int i = blockIdx.x * 256 + threadIdx.x;
  if (i < n) p[i] = 0;
}

// ---------------- weight prep (SAGE): hi/lo bf16 split, k-chunk-major ----------------
// slots/layer: 0=Wl[l,0] 1=Wl[l,3] 2=Wr[l,0]+Wr[l,3] 3=Wl[l,1] 4=Wr[l,1] 5=Wl[l,2] 6=Wr[l,2]
// Wt[slot][kc(32: 0..15 hi, 16..31 lo)][n(128)][e(8)] u16 — 16B per (kc,n) fragment.
// MFMA B frag for (kw,l4,n): kc = kw*4+l4 (hi), +16 (lo) -> conflict-free LDS reads.
__global__ void wprep_kernel(const float* __restrict__ Wl, const float* __restrict__ Wr,
                             u16* __restrict__ Wt) {
  int g = blockIdx.x;          // 0..20
  int l = g / 7, slot = g % 7;
  size_t base = (size_t)l * 4 * HD * HD;
  const float* A = nullptr; const float* Bm = nullptr;
  switch (slot) {
    case 0: A = Wl + base + (size_t)0 * HD * HD; break;
    case 1: A = Wl + base + (size_t)3 * HD * HD; break;
    case 2: A = Wr + base + (size_t)0 * HD * HD; Bm = Wr + base + (size_t)3 * HD * HD; break;
    case 3: A = Wl + base + (size_t)1 * HD * HD; break;
    case 4: A = Wr + base + (size_t)1 * HD * HD; break;
    case 5: A = Wl + base + (size_t)2 * HD * HD; break;
    case 6: A = Wr + base + (size_t)2 * HD * HD; break;
  }
  u16* Wd = Wt + (size_t)g * 32 * 128 * 8;
  int tid = threadIdx.x;
  for (int i = 0; i < 64; ++i) {
    int idx = i * 256 + tid;   // = k*128 + n  (k,n in 0..127)
    int k = idx >> 7, n = idx & 127;
    float wv = A[idx] + (Bm ? Bm[idx] : 0.0f);
    u16 hi = f2bf(wv);
    float lo = wv - bf2f(hi);
    Wd[(size_t)(k >> 3) * 1024 + n * 8 + (k & 7)] = hi;
    Wd[(size_t)((k >> 3) + 16) * 1024 + n * 8 + (k & 7)] = f2bf(lo);
  }
}

// ---------------- weight prep (proj): Wp[type][mat(2)][n(128)][k(32)] ----------------
__global__ void wprep_proj_kernel(const float* __restrict__ W0, const float* __restrict__ W1,
                                  const float* __restrict__ W2, u16* __restrict__ Wp) {
  int t = blockIdx.x;  // 3
  const float* W = t == 0 ? W0 : t == 1 ? W1 : W2;
  int F = t == 0 ? 16 : t == 1 ? 10 : 8;
  u16* dst = Wp + (size_t)t * 2 * 128 * 32;
  for (int i = threadIdx.x; i < 128 * 32; i += 256) {
    int n = i >> 5, k = i & 31;
    int f = k & 15;
    float wv = (f < F) ? W[f * 128 + n] : 0.f;
    u16 hi = f2bf(wv);
    float lo = wv - bf2f(hi);
    dst[(size_t)n * 32 + k] = hi;
    dst[(size_t)128 * 32 + n * 32 + k] = f2bf(lo);
  }
}

// ---------------- combined bias ----------------
__global__ void bias_prep_kernel(const float* __restrict__ cb, float* __restrict__ bcomb) {
  int i = blockIdx.x * 256 + threadIdx.x;
  if (i >= NLAY * 3 * HD) return;
  int l = i / (3 * HD), r = (i % (3 * HD)) / HD, c = i % HD;
  const float* b = cb + (size_t)l * 4 * HD;
  float v;
  if (r == 0) v = b[0 * HD + c] + b[3 * HD + c];
  else if (r == 1) v = b[1 * HD + c];
  else v = b[2 * HD + c];
  bcomb[i] = v;
}

// ---------------- batch segment bounds ----------------
__global__ void seg_kernel(const int* __restrict__ b0, const int* __restrict__ b1,
                           const int* __restrict__ b2, int* __restrict__ seg) {
  int tid = threadIdx.x;  // 256
  for (int t = 0; t < 3; ++t) {
    const int* bt = t == 0 ? b0 : t == 1 ? b1 : b2;
    int n = t == 0 ? NH_N : t == 1 ? NV_N : NE_N;
    seg[t * 257 + tid] = lower_bound_i(bt, n, tid);
    if (tid == 0) seg[t * 257 + 256] = n;
  }
}

// ---------------- CSR build over 4 concatenated relations ----------------
__global__ void hist_all_kernel(const int* __restrict__ d0, const int* __restrict__ d1,
                                const int* __restrict__ d2, const int* __restrict__ d3,
                                int* __restrict__ deg) {
  int e = blockIdx.x * 256 + threadIdx.x;
  if (e >= E_N) return;
  int r = blockIdx.y;
  const int* ds = r == 0 ? d0 : r == 1 ? d1 : r == 2 ? d2 : d3;
  int ofs = r == 0 ? 0 : r == 1 ? NV_N : r == 2 ? (NV_N + NH_N) : (NV_N + NH_N + NE_N);
  atomicAdd(&deg[ofs + ds[e]], 1);
}

__global__ void scan_block_kernel(const int* __restrict__ deg, int* __restrict__ rp,
                                  int* __restrict__ bsums, int n) {
  __shared__ int buf[256];
  int tid = threadIdx.x;
  int i = blockIdx.x * 256 + tid;
  buf[tid] = (i < n) ? deg[i] : 0;
  __syncthreads();
  #pragma unroll
  for (int off = 1; off < 256; off <<= 1) {
    int t = (tid >= off) ? buf[tid - off] : 0;
    __syncthreads();
    buf[tid] += t;
    __syncthreads();
  }
  if (i < n) rp[i + 1] = buf[tid];
  if (tid == 255) bsums[blockIdx.x] = buf[255];
}

__global__ void scan_sums_kernel(int* __restrict__ bsums, int nb) {
  __shared__ int buf[256];
  __shared__ int carry_s;
  int tid = threadIdx.x;
  if (tid == 0) carry_s = 0;
  __syncthreads();
  for (int base = 0; base < nb; base += 256) {
    int i = base + tid;
    buf[tid] = (i < nb) ? bsums[i] : 0;
    __syncthreads();
    for (int off = 1; off < 256; off <<= 1) {
      int t = (tid >= off) ? buf[tid - off] : 0;
      __syncthreads();
      buf[tid] += t;
      __syncthreads();
    }
    int c = carry_s;
    if (i < nb) bsums[i] = buf[tid] + c;
    __syncthreads();
    if (tid == 255) carry_s = c + buf[255];
    __syncthreads();
  }
}

__global__ void scan_add_kernel(const int* __restrict__ bsums, int* __restrict__ rp, int n) {
  int i = blockIdx.x * 256 + threadIdx.x;
  if (i == 0) rp[0] = 0;
  if (i < n && blockIdx.x > 0) rp[i + 1] += bsums[blockIdx.x - 1];
}

__global__ void fill_all_kernel(const int* __restrict__ s0, const int* __restrict__ s1,
                                const int* __restrict__ s2, const int* __restrict__ s3,
                                const int* __restrict__ d0, const int* __restrict__ d1,
                                const int* __restrict__ d2, const int* __restrict__ d3,
                                const int* __restrict__ rp, int* __restrict__ fil,
                                int* __restrict__ csr) {
  int e = blockIdx.x * 256 + threadIdx.x;
  if (e >= E_N) return;
  int r = blockIdx.y;
  const int* ss = r == 0 ? s0 : r == 1 ? s1 : r == 2 ? s2 : s3;
  const int* ds = r == 0 ? d0 : r == 1 ? d1 : r == 2 ? d2 : d3;
  int ofs = r == 0 ? 0 : r == 1 ? NV_N : r == 2 ? (NV_N + NH_N) : (NV_N + NH_N + NE_N);
  int d = ofs + ds[e];
  int pos = rp[d] + atomicAdd(&fil[d], 1);
  csr[pos] = ss[e];
}

// ---------------- MFMA input projection ----------------
__global__ __launch_bounds__(256)
void proj_mfma_kernel(const float* __restrict__ x0, const float* __restrict__ x1,
                      const float* __restrict__ x2, const u16* __restrict__ Wp,
                      const float* __restrict__ bb0, const float* __restrict__ bb1,
                      const float* __restrict__ bb2,
                      u16* __restrict__ o0, u16* __restrict__ o1, u16* __restrict__ o2) {
  __shared__ u16 xs[64 * 32];  // 4KB
  int blk = blockIdx.x;
  const float* x; const float* bs; u16* o; int F, M, row0, t;
  if (blk < NBH)            { t = 0; x = x0; bs = bb0; o = o0; F = 16; M = NH_N; row0 = blk * 64; }
  else if (blk < NBH + NBV) { t = 1; x = x1; bs = bb1; o = o1; F = 10; M = NV_N; row0 = (blk - NBH) * 64; }
  else                      { t = 2; x = x2; bs = bb2; o = o2; F = 8;  M = NE_N; row0 = (blk - NBH - NBV) * 64; }
  const int tid = threadIdx.x;
  const int lane = tid & 63;
  const int w = tid >> 6;
  const int l15 = lane & 15;
  const int l4 = lane >> 4;

  *(uint4*)((char*)xs + tid * 16) = make_uint4(0, 0, 0, 0);
  __syncthreads();
  int total = 64 * F;
  for (int i = tid; i < total; i += 256) {
    int row = i / F, f = i % F;
    int gr = row0 + row; if (gr >= M) gr = M - 1;
    float v = x[(size_t)gr * F + f];
    u16 hi = f2bf(v);
    float lo = v - bf2f(hi);
    *(u16*)((char*)xs + ((row * 64 + f * 2) ^ ((row & 3) << 4))) = hi;
    *(u16*)((char*)xs + ((row * 64 + (f + 16) * 2) ^ ((row & 3) << 4))) = f2bf(lo);
  }
  __syncthreads();

  int arow = w * 16 + l15;
  short8v af = *(const short8v*)((const char*)xs + ((arow * 64 + l4 * 16) ^ ((arow & 3) << 4)));
  const u16* Wp_t = Wp + (size_t)t * 2 * 128 * 32;
  f32x4 acc[8];
  #pragma unroll
  for (int ni = 0; ni < 8; ++ni) {
    const u16* bp = Wp_t + (size_t)(ni * 16 + l15) * 32 + l4 * 8;
    short8v b1 = *(const short8v*)bp;
    short8v b2 = *(const short8v*)(bp + 128 * 32);
    f32x4 a0 = (f32x4){0.f, 0.f, 0.f, 0.f};
    a0 = __builtin_amdgcn_mfma_f32_16x16x32_bf16(af, b1, a0, 0, 0, 0);
    a0 = __builtin_amdgcn_mfma_f32_16x16x32_bf16(af, b2, a0, 0, 0, 0);
    acc[ni] = a0;
  }
  #pragma unroll
  for (int ni = 0; ni < 8; ++ni) {
    int col = ni * 16 + l15;
    float bv = bs[col];
    #pragma unroll
    for (int r = 0; r < 4; ++r) {
      int gr = row0 + w * 16 + l4 * 4 + r;
      if (gr >= M) continue;
      o[(size_t)gr * HD + col] = f2bf(fmaxf(acc[ni][r] + bv, 0.f));
    }
  }
}

// ---------------- gather-mean kernel (latency-optimized, no LDS, max occupancy) ----------------
__global__ __launch_bounds__(256)
void gather_layer_kernel(const u16* __restrict__ ch, const u16* __restrict__ cv,
                         const u16* __restrict__ ce, const int* __restrict__ csr,
                         const int* __restrict__ rp_hv, const int* __restrict__ rp_ev,
                         const int* __restrict__ rp_vh, const int* __restrict__ rp_ve,
                         u16* __restrict__ mv0, u16* __restrict__ mv1,
                         u16* __restrict__ mh, u16* __restrict__ me) {
  int blk = blockIdx.x;
  const u16* S; const int* rp; u16* mout; int M, row0;
  if (blk < GB_HV)                 { S = ch; rp = rp_hv; mout = mv0; M = NV_N; row0 = blk * 32; }
  else if (blk < GB_HV + GB_EV)    { S = ce; rp = rp_ev; mout = mv1; M = NV_N; row0 = (blk - GB_HV) * 32; }
  else if (blk < GB_HV + GB_EV + GB_VH) { S = cv; rp = rp_vh; mout = mh; M = NH_N; row0 = (blk - GB_HV - GB_EV) * 32; }
  else                             { S = cv; rp = rp_ve; mout = me; M = NE_N; row0 = (blk - GB_HV - GB_EV - GB_VH) * 32; }

  const int c8 = threadIdx.x & 7;
  const int gm = threadIdx.x >> 3;
  int ggr = row0 + gm; if (ggr >= M) ggr = M - 1;
  int s0 = rp[ggr], s1 = rp[ggr + 1];

  float fa[16];
  #pragma unroll
  for (int q = 0; q < 16; ++q) fa[q] = 0.f;

  int j = s0;
  for (; j + 3 < s1; j += 4) {
    int i0 = csr[j], i1 = csr[j + 1], i2 = csr[j + 2], i3 = csr[j + 3];
    const u16* p0 = S + (size_t)i0 * HD + c8 * 16;
    const u16* p1 = S + (size_t)i1 * HD + c8 * 16;
    const u16* p2 = S + (size_t)i2 * HD + c8 * 16;
    const u16* p3 = S + (size_t)i3 * HD + c8 * 16;
    short8v a0 = *(const short8v*)p0, a1 = *(const short8v*)(p0 + 8);
    short8v b0 = *(const short8v*)p1, b1 = *(const short8v*)(p1 + 8);
    short8v c0 = *(const short8v*)p2, c1 = *(const short8v*)(p2 + 8);
    short8v d0 = *(const short8v*)p3, d1 = *(const short8v*)(p3 + 8);
    #pragma unroll
    for (int q = 0; q < 8; ++q) {
      fa[q]     += (bf2f((u16)a0[q]) + bf2f((u16)b0[q])) + (bf2f((u16)c0[q]) + bf2f((u16)d0[q]));
      fa[8 + q] += (bf2f((u16)a1[q]) + bf2f((u16)b1[q])) + (bf2f((u16)c1[q]) + bf2f((u16)d1[q]));
    }
  }
  for (; j < s1; ++j) {
    const u16* p0 = S + (size_t)csr[j] * HD + c8 * 16;
    short8v a0 = *(const short8v*)p0, a1 = *(const short8v*)(p0 + 8);
    #pragma unroll
    for (int q = 0; q < 8; ++q) {
      fa[q] += bf2f((u16)a0[q]);
      fa[8 + q] += bf2f((u16)a1[q]);
    }
  }

  int cnt = s1 - s0; if (cnt < 1) cnt = 1;
  float inv = 1.f / (float)cnt;
  unsigned pw[8];
  #pragma unroll
  for (int q = 0; q < 8; ++q) {
    unsigned lo16 = f2bf(fa[2 * q] * inv);
    unsigned hi16 = f2bf(fa[2 * q + 1] * inv);
    pw[q] = lo16 | (hi16 << 16);
  }
  u16* wr_ = mout + (size_t)ggr * HD + c8 * 16;
  *(uint4*)wr_ = make_uint4(pw[0], pw[1], pw[2], pw[3]);
  *(uint4*)(wr_ + 8) = make_uint4(pw[4], pw[5], pw[6], pw[7]);
}

// ---------------- GEMM kernel: W resident (conflict-free layout), X reg-prefetch pipeline ----
// Block = (type, col-half, 4 consecutive 64-row tiles). Stage seq: (t,s) pairs.
// Per stage: commit prefetched X regs -> LDS; issue next stage's X loads (hide under MFMA);
// barrier; MFMA from LDS only. W LDS layout [kc32][n64][16B]: bank=(n&7)*4, even 8-way.
extern __shared__ char smem[];
__global__ __launch_bounds__(256)
void gemm_layer_kernel(const u16* __restrict__ mv0, const u16* __restrict__ mv1,
                       const u16* __restrict__ mh, const u16* __restrict__ me,
                       const u16* __restrict__ cv, const u16* __restrict__ ch,
                       const u16* __restrict__ ce,
                       u16* __restrict__ nv, u16* __restrict__ nh, u16* __restrict__ ne,
                       const u16* __restrict__ Wt_l, const float* __restrict__ bcomb_l) {
  int blk = blockIdx.x;
  int type, half, t0;
  if (blk < 2 * BV)               { type = 0; half = blk >= BV; t0 = (blk % BV) * TPB; }
  else if (blk < 2 * (BV + BH))   { int r = blk - 2 * BV; type = 1; half = r >= BH; t0 = (r % BH) * TPB; }
  else                            { int r = blk - 2 * (BV + BH); type = 2; half = r >= BE; t0 = (r % BE) * TPB; }
  const int ntl = type == 0 ? TV : type == 1 ? TH : TE;
  int nt = ntl - t0; if (nt > TPB) nt = TPB;
  const int nslot = type == 0 ? 3 : 2;
  const int M = type == 0 ? NV_N : type == 1 ? NH_N : NE_N;
  const int mode = type == 0 ? 2 : 0;
  const u16* Xsrc[3];
  if (type == 0)      { Xsrc[0] = mv0; Xsrc[1] = mv1; Xsrc[2] = cv; }
  else if (type == 1) { Xsrc[0] = mh;  Xsrc[1] = ch;  Xsrc[2] = ch; }
  else                { Xsrc[0] = me;  Xsrc[1] = ce;  Xsrc[2] = ce; }
  const u16* Wg0 = Wt_l + (size_t)(type == 0 ? 0 : type == 1 ? 3 : 5) * 32 * 128 * 8;
  u16* outp = type == 0 ? nv : type == 1 ? nh : ne;
  const float* bi = bcomb_l + (type == 0 ? 0 : type == 1 ? 128 : 256);

  const int tid = threadIdx.x;
  const int lane = tid & 63;
  const int w = tid >> 6;
  const int l15 = lane & 15;
  const int l4 = lane >> 4;
  const int mrow = w * 16 + l15;

  // ---- stage W (this half's 64 cols) into LDS: [kc32][n64][16B], linear ----
  for (int s = 0; s < nslot; ++s) {
    const u16* Wg = Wg0 + (size_t)s * 32 * 128 * 8;
    char* wb = smem + s * 32768;
    for (int i = tid; i < 2048; i += 256) {
      int kc = i >> 6, nl = i & 63;
      uint4 v = *(const uint4*)(Wg + ((size_t)kc * 128 + half * 64 + nl) * 8);
      *(uint4*)(wb + i * 16) = v;
    }
  }
  char* xb = smem + 3 * 32768;

  const int nst = nt * nslot;
  // prologue: prefetch stage 0's X tile into registers
  uint4 pf[4];
  {
    const u16* Xg = Xsrc[0];
    int row0 = t0 * 64;
    #pragma unroll
    for (int i = 0; i < 4; ++i) {
      int idx = i * 256 + tid, m = idx >> 4, cc = idx & 15;
      int gr = row0 + m; if (gr >= M) gr = M - 1;
      pf[i] = *(const uint4*)(Xg + (size_t)gr * HD + cc * 8);
    }
  }

  f32x4 acc[4];
  for (int st = 0; st < nst; ++st) {
    int t = st / nslot;
    int s = st - t * nslot;
    if (s == 0) {
      #pragma unroll
      for (int ni = 0; ni < 4; ++ni) acc[ni] = (f32x4){0.f, 0.f, 0.f, 0.f};
    }
    __syncthreads();  // all waves done reading xb (and, at st=0, W staged)
    // commit current stage's X to LDS (swizzled)
    #pragma unroll
    for (int i = 0; i < 4; ++i) {
      int idx = i * 256 + tid, m = idx >> 4, cc = idx & 15;
      *(uint4*)(xb + m * 256 + ((cc * 16) ^ ((m & 7) << 4))) = pf[i];
    }
    // issue next stage's loads (latency hides under barrier + MFMA)
    if (st + 1 < nst) {
      int t2 = (st + 1) / nslot;
      int s2 = (st + 1) - t2 * nslot;
      const u16* Xg = Xsrc[s2];
      int row0n = (t0 + t2) * 64;
      #pragma unroll
      for (int i = 0; i < 4; ++i) {
        int idx = i * 256 + tid, m = idx >> 4, cc = idx & 15;
        int gr = row0n + m; if (gr >= M) gr = M - 1;
        pf[i] = *(const uint4*)(Xg + (size_t)gr * HD + cc * 8);
      }
    }
    __syncthreads();  // xb ready
    const char* wb = smem + s * 32768;
    #pragma unroll
    for (int kw = 0; kw < 4; ++kw) {
      int kb = kw * 64 + l4 * 16;
      short8v a = *(const short8v*)(xb + mrow * 256 + (kb ^ ((mrow & 7) << 4)));
      int kcw = kw * 4 + l4;
      #pragma unroll
      for (int ni = 0; ni < 4; ++ni) {
        int nlcl = ni * 16 + l15;
        const char* bp = wb + ((size_t)kcw * 64 + nlcl) * 16;
        short8v bh_ = *(const short8v*)bp;
        short8v bl_ = *(const short8v*)(bp + 16384);
        acc[ni] = __builtin_amdgcn_mfma_f32_16x16x32_bf16(a, bh_, acc[ni], 0, 0, 0);
        acc[ni] = __builtin_amdgcn_mfma_f32_16x16x32_bf16(a, bl_, acc[ni], 0, 0, 0);
      }
    }
    if (s == nslot - 1) {
      int row0 = (t0 + t) * 64;
      #pragma unroll
      for (int ni = 0; ni < 4; ++ni) {
        int col = half * 64 + ni * 16 + l15;
        float bv = bi[col];
        #pragma unroll
        for (int r = 0; r < 4; ++r) {
          int gr = row0 + w * 16 + l4 * 4 + r;
          if (gr >= M) continue;
          float v = acc[ni][r] + bv;
          v = (mode == 2) ? fmaxf(0.5f * v, 0.f) : fmaxf(v, 0.f);
          outp[(size_t)gr * HD + col] = f2bf(v);
        }
      }
    }
  }
}

// ---------------- parallel batched mean pool ----------------
__global__ void pool_kernel(const u16* __restrict__ f0, const u16* __restrict__ f1,
                            const u16* __restrict__ f2, const int* __restrict__ seg,
                            float* __restrict__ pooled) {
  int t = blockIdx.z;
  const u16* hx = t == 0 ? f0 : t == 1 ? f1 : f2;
  int b = blockIdx.x, s = blockIdx.y, h = threadIdx.x;
  int lo = seg[t * 257 + b], hi = seg[t * 257 + b + 1];
  int len = hi - lo;
  int a0 = lo + (len * s) / PS, a1 = lo + (len * (s + 1)) / PS;
  float acc = 0.f;
  for (int i = a0; i < a1; ++i) acc += bf2f(hx[(size_t)i * HD + h]);
  if (a1 > a0) atomicAdd(&pooled[(size_t)b * 384 + t * 128 + h], acc);
}

// ---------------- final dense ----------------
__global__ void final_kernel(const float* __restrict__ pooled, const float* __restrict__ scalars,
                             const int* __restrict__ seg, const float* __restrict__ Wf,
                             const float* __restrict__ bf, float* __restrict__ out) {
  int b = blockIdx.x;
  int j = threadIdx.x;  // 128
  float iv[3];
  #pragma unroll
  for (int t = 0; t < 3; ++t) {
    int c = seg[t * 257 + b + 1] - seg[t * 257 + b];
    if (c < 1) c = 1;
    iv[t] = 1.f / (float)c;
  }
  float acc = bf[j];
  const float* pr = pooled + (size_t)b * 384;
  #pragma unroll
  for (int t = 0; t < 3; ++t)
    for (int k = 0; k < 128; ++k)
      acc = fmaf(pr[t * 128 + k] * iv[t], Wf[(size_t)(t * 128 + k) * 128 + j], acc);
  const float* sr = scalars + (size_t)b * NSCA;
  for (int s = 0; s < NSCA; ++s) acc = fmaf(sr[s], Wf[(size_t)(384 + s) * 128 + j], acc);
  out[(size_t)b * 128 + j] = acc;
}

extern "C" void kernel_launch(void* const* d_in, const int* in_sizes, int n_in,
                              void* d_out, int out_size, void* d_ws, size_t ws_size,
                              hipStream_t stream) {
  const float* x_hex   = (const float*)d_in[0];
  const float* x_vert  = (const float*)d_in[1];
  const float* x_edge  = (const float*)d_in[2];
  const float* scalars = (const float*)d_in[3];
  const int* src_hv = (const int*)d_in[4];
  const int* dst_hv = (const int*)d_in[5];
  const int* src_vh = (const int*)d_in[6];
  const int* dst_vh = (const int*)d_in[7];
  const int* src_ve = (const int*)d_in[8];
  const int* dst_ve = (const int*)d_in[9];
  const int* src_ev = (const int*)d_in[10];
  const int* dst_ev = (const int*)d_in[11];
  const int* batch_hex  = (const int*)d_in[12];
  const int* batch_vert = (const int*)d_in[13];
  const int* batch_edge = (const int*)d_in[14];
  const float* W_ph = (const float*)d_in[15];
  const float* b_ph = (const float*)d_in[16];
  const float* W_pv = (const float*)d_in[17];
  const float* b_pv = (const float*)d_in[18];
  const float* W_pe = (const float*)d_in[19];
  const float* b_pe = (const float*)d_in[20];
  const float* conv_Wl = (const float*)d_in[21];
  const float* conv_Wr = (const float*)d_in[22];
  const float* conv_b  = (const float*)d_in[23];
  const float* W_final = (const float*)d_in[24];
  const float* b_final = (const float*)d_in[25];
  float* out = (float*)d_out;

  // ---- workspace layout (~268 MB) ----
  char* wp = (char*)d_ws;
  size_t off = 0;
  auto alloc = [&](size_t bytes) -> void* {
    void* p = wp + off;
    off += (bytes + 511) & ~(size_t)511;
    return p;
  };
  u16* hbuf[2]; u16* vbuf[2]; u16* ebuf[2];
  hbuf[0] = (u16*)alloc((size_t)NH_N * HD * 2);
  hbuf[1] = (u16*)alloc((size_t)NH_N * HD * 2);
  vbuf[0] = (u16*)alloc((size_t)NV_N * HD * 2);
  vbuf[1] = (u16*)alloc((size_t)NV_N * HD * 2);
  ebuf[0] = (u16*)alloc((size_t)NE_N * HD * 2);
  ebuf[1] = (u16*)alloc((size_t)NE_N * HD * 2);
  u16* mv0 = (u16*)alloc((size_t)NV_N * HD * 2);
  u16* mv1 = (u16*)alloc((size_t)NV_N * HD * 2);
  u16* mh  = (u16*)alloc((size_t)NH_N * HD * 2);
  u16* me  = (u16*)alloc((size_t)NE_N * HD * 2);
  u16* Wt = (u16*)alloc((size_t)21 * 32 * 128 * 8 * 2);
  u16* Wp = (u16*)alloc((size_t)3 * 2 * 128 * 32 * 2);
  int* deg_all = (int*)alloc((size_t)800000 * 4);
  float* pooled = (float*)alloc((size_t)NBAT * 384 * 4);
  int* fil_all = deg_all + 400000;
  int* rp_all  = (int*)alloc((size_t)400001 * 4);
  int* csr_all = (int*)alloc((size_t)4 * E_N * 4);
  int* bsums   = (int*)alloc(2048 * 4);
  int* seg     = (int*)alloc(3 * 257 * 4);
  float* bcomb = (float*)alloc((size_t)NLAY * 3 * HD * 4);

  const int OFS_HV = 0;
  const int OFS_VH = NV_N;
  const int OFS_VE = NV_N + NH_N;
  const int OFS_EV = NV_N + NH_N + NE_N;
  const int NDEG = 400000;

  // ---- prep ----
  wprep_kernel<<<21, 256, 0, stream>>>(conv_Wl, conv_Wr, Wt);
  wprep_proj_kernel<<<3, 256, 0, stream>>>(W_ph, W_pv, W_pe, Wp);
  bias_prep_kernel<<<(NLAY * 3 * HD + 255) / 256, 256, 0, stream>>>(conv_b, bcomb);
  zero_kernel<<<(800000 + NBAT * 384 + 255) / 256, 256, 0, stream>>>(deg_all, 800000 + NBAT * 384);
  seg_kernel<<<1, 256, 0, stream>>>(batch_hex, batch_vert, batch_edge, seg);

  // ---- CSR build ----
  hist_all_kernel<<<dim3((E_N + 255) / 256, 4), 256, 0, stream>>>(dst_hv, dst_vh, dst_ve, dst_ev, deg_all);
  int nb = (NDEG + 255) / 256;
  scan_block_kernel<<<nb, 256, 0, stream>>>(deg_all, rp_all, bsums, NDEG);
  scan_sums_kernel<<<1, 256, 0, stream>>>(bsums, nb);
  scan_add_kernel<<<nb, 256, 0, stream>>>(bsums, rp_all, NDEG);
  fill_all_kernel<<<dim3((E_N + 255) / 256, 4), 256, 0, stream>>>(
      src_hv, src_vh, src_ve, src_ev, dst_hv, dst_vh, dst_ve, dst_ev, rp_all, fil_all, csr_all);

  // ---- input projections (MFMA) ----
  u16 *ch = hbuf[0], *cv = vbuf[0], *ce = ebuf[0];
  u16 *nh = hbuf[1], *nv = vbuf[1], *ne = ebuf[1];
  proj_mfma_kernel<<<NBH + NBV + NBE, 256, 0, stream>>>(
      x_hex, x_vert, x_edge, Wp, b_ph, b_pv, b_pe, ch, cv, ce);

  // ---- layers: gather (latency-regime) + GEMM (compute-regime) ----
  const int* rp_hv = rp_all + OFS_HV;
  const int* rp_vh = rp_all + OFS_VH;
  const int* rp_ve = rp_all + OFS_VE;
  const int* rp_ev = rp_all + OFS_EV;
  for (int l = 0; l < NLAY; ++l) {
    const u16* Wt_l = Wt + (size_t)(l * 7) * 32 * 128 * 8;
    const float* bcomb_l = bcomb + (size_t)(l * 3) * HD;

    gather_layer_kernel<<<GB_TOT, 256, 0, stream>>>(
        ch, cv, ce, csr_all, rp_hv, rp_ev, rp_vh, rp_ve, mv0, mv1, mh, me);
    gemm_layer_kernel<<<GEMM_BLOCKS, 256, GEMM_LDS, stream>>>(
        mv0, mv1, mh, me, cv, ch, ce, nv, nh, ne, Wt_l, bcomb_l);

    u16* t;
    t = ch; ch = nh; nh = t;
    t = cv; cv = nv; nv = t;
    t = ce; ce = ne; ne = t;
  }

  // ---- pooling + final dense ----
  pool_kernel<<<dim3(NBAT, PS, 3), 128, 0, stream>>>(ch, cv, ce, seg, pooled);
  final_kernel<<<NBAT, 128, 0, stream>>>(pooled, scalars, seg, W_final, b_final, out);
}

// Round 12
// 980.801 us; speedup vs baseline: 1.4091x; 1.4091x over previous
//
#include <hip/hip_runtime.h>
#include <hip/hip_bf16.h>

#define NH_N 50000
#define NV_N 100000
#define NE_N 150000
#define E_N  300000
#define HD   128
#define NLAY 3
#define NBAT 256
#define NSCA 22
#define PS   8   // pool row splits

// proj grid split (64-row tiles)
#define NBH 782    // ceil(50000/64)
#define NBV 1563   // ceil(100000/64)
#define NBE 2344   // ceil(150000/64)

// gather grid: 32 rows/block
#define GB_HV 3125   // NV/32
#define GB_EV 3125
#define GB_VH 1563   // ceil(50000/32)
#define GB_VE 4688   // ceil(150000/32)
#define GB_TOT (GB_HV + GB_EV + GB_VH + GB_VE)  // 12501

// gemm grid: 64-row x 128-col tiles (full width), 4 tiles/block
#define TV 1563
#define TH 782
#define TE 2344
#define TPB 4
#define BV 391   // ceil(1563/4)
#define BH 196   // ceil(782/4)
#define BE 586   // ceil(2344/4)
#define GEMM_BLOCKS (BV + BH + BE)   // 1173
#define WSLOT (16 * 128 * 8)         // u16 per W slot (hi only, kc-major)
#define GEMM_LDS (3*32768 + 16384)   // 114688

typedef unsigned short u16;
typedef __attribute__((ext_vector_type(8))) short short8v;
typedef __attribute__((ext_vector_type(4))) float f32x4;

__device__ inline u16 f2bf(float f) { __hip_bfloat16 h = __float2bfloat16(f); return *(u16*)&h; }
__device__ inline float bf2f(u16 u) { __hip_bfloat16 h; *(u16*)&h = u; return __bfloat162float(h); }

__device__ inline int lower_bound_i(const int* __restrict__ a, int n, int v) {
  int lo = 0, hi = n;
  while (lo < hi) { int m = (lo + hi) >> 1; if (a[m] < v) lo = m + 1; else hi = m; }
  return lo;
}

// ---------------- zero fill ----------------
__global__ void zero_kernel(int* __restrict__ p, int n) {
  int i = blockIdx.x * 256 + threadIdx.x;
  if (i < n) p[i] = 0;
}

// ---------------- weight prep (SAGE): bf16, k-chunk-major (conflict-free LDS reads) ----
// slots/layer: 0=Wl[l,0] 1=Wl[l,3] 2=Wr[l,0]+Wr[l,3] 3=Wl[l,1] 4=Wr[l,1] 5=Wl[l,2] 6=Wr[l,2]
// Wt[slot][kc(16)][n(128)][e(8)] u16 — 16B fragment per (kc,n).
__global__ void wprep_kernel(const float* __restrict__ Wl, const float* __restrict__ Wr,
                             u16* __restrict__ Wt) {
  int g = blockIdx.x;          // 0..20
  int l = g / 7, slot = g % 7;
  size_t base = (size_t)l * 4 * HD * HD;
  const float* A = nullptr; const float* Bm = nullptr;
  switch (slot) {
    case 0: A = Wl + base + (size_t)0 * HD * HD; break;
    case 1: A = Wl + base + (size_t)3 * HD * HD; break;
    case 2: A = Wr + base + (size_t)0 * HD * HD; Bm = Wr + base + (size_t)3 * HD * HD; break;
    case 3: A = Wl + base + (size_t)1 * HD * HD; break;
    case 4: A = Wr + base + (size_t)1 * HD * HD; break;
    case 5: A = Wl + base + (size_t)2 * HD * HD; break;
    case 6: A = Wr + base + (size_t)2 * HD * HD; break;
  }
  u16* Wd = Wt + (size_t)g * WSLOT;
  int tid = threadIdx.x;
  for (int i = 0; i < 64; ++i) {
    int idx = i * 256 + tid;   // = k*128 + n  (k,n in 0..127)
    int k = idx >> 7, n = idx & 127;
    float wv = A[idx] + (Bm ? Bm[idx] : 0.0f);
    Wd[(size_t)(k >> 3) * 1024 + n * 8 + (k & 7)] = f2bf(wv);
  }
}

// ---------------- weight prep (proj): Wp[type][mat(2)][n(128)][k(32)] (hi/lo kept) ------
__global__ void wprep_proj_kernel(const float* __restrict__ W0, const float* __restrict__ W1,
                                  const float* __restrict__ W2, u16* __restrict__ Wp) {
  int t = blockIdx.x;  // 3
  const float* W = t == 0 ? W0 : t == 1 ? W1 : W2;
  int F = t == 0 ? 16 : t == 1 ? 10 : 8;
  u16* dst = Wp + (size_t)t * 2 * 128 * 32;
  for (int i = threadIdx.x; i < 128 * 32; i += 256) {
    int n = i >> 5, k = i & 31;
    int f = k & 15;
    float wv = (f < F) ? W[f * 128 + n] : 0.f;
    u16 hi = f2bf(wv);
    float lo = wv - bf2f(hi);
    dst[(size_t)n * 32 + k] = hi;
    dst[(size_t)128 * 32 + n * 32 + k] = f2bf(lo);
  }
}

// ---------------- combined bias ----------------
__global__ void bias_prep_kernel(const float* __restrict__ cb, float* __restrict__ bcomb) {
  int i = blockIdx.x * 256 + threadIdx.x;
  if (i >= NLAY * 3 * HD) return;
  int l = i / (3 * HD), r = (i % (3 * HD)) / HD, c = i % HD;
  const float* b = cb + (size_t)l * 4 * HD;
  float v;
  if (r == 0) v = b[0 * HD + c] + b[3 * HD + c];
  else if (r == 1) v = b[1 * HD + c];
  else v = b[2 * HD + c];
  bcomb[i] = v;
}

// ---------------- batch segment bounds ----------------
__global__ void seg_kernel(const int* __restrict__ b0, const int* __restrict__ b1,
                           const int* __restrict__ b2, int* __restrict__ seg) {
  int tid = threadIdx.x;  // 256
  for (int t = 0; t < 3; ++t) {
    const int* bt = t == 0 ? b0 : t == 1 ? b1 : b2;
    int n = t == 0 ? NH_N : t == 1 ? NV_N : NE_N;
    seg[t * 257 + tid] = lower_bound_i(bt, n, tid);
    if (tid == 0) seg[t * 257 + 256] = n;
  }
}

// ---------------- CSR build over 4 concatenated relations ----------------
__global__ void hist_all_kernel(const int* __restrict__ d0, const int* __restrict__ d1,
                                const int* __restrict__ d2, const int* __restrict__ d3,
                                int* __restrict__ deg) {
  int e = blockIdx.x * 256 + threadIdx.x;
  if (e >= E_N) return;
  int r = blockIdx.y;
  const int* ds = r == 0 ? d0 : r == 1 ? d1 : r == 2 ? d2 : d3;
  int ofs = r == 0 ? 0 : r == 1 ? NV_N : r == 2 ? (NV_N + NH_N) : (NV_N + NH_N + NE_N);
  atomicAdd(&deg[ofs + ds[e]], 1);
}

__global__ void scan_block_kernel(const int* __restrict__ deg, int* __restrict__ rp,
                                  int* __restrict__ bsums, int n) {
  __shared__ int buf[256];
  int tid = threadIdx.x;
  int i = blockIdx.x * 256 + tid;
  buf[tid] = (i < n) ? deg[i] : 0;
  __syncthreads();
  #pragma unroll
  for (int off = 1; off < 256; off <<= 1) {
    int t = (tid >= off) ? buf[tid - off] : 0;
    __syncthreads();
    buf[tid] += t;
    __syncthreads();
  }
  if (i < n) rp[i + 1] = buf[tid];
  if (tid == 255) bsums[blockIdx.x] = buf[255];
}

__global__ void scan_sums_kernel(int* __restrict__ bsums, int nb) {
  __shared__ int buf[256];
  __shared__ int carry_s;
  int tid = threadIdx.x;
  if (tid == 0) carry_s = 0;
  __syncthreads();
  for (int base = 0; base < nb; base += 256) {
    int i = base + tid;
    buf[tid] = (i < nb) ? bsums[i] : 0;
    __syncthreads();
    for (int off = 1; off < 256; off <<= 1) {
      int t = (tid >= off) ? buf[tid - off] : 0;
      __syncthreads();
      buf[tid] += t;
      __syncthreads();
    }
    int c = carry_s;
    if (i < nb) bsums[i] = buf[tid] + c;
    __syncthreads();
    if (tid == 255) carry_s = c + buf[255];
    __syncthreads();
  }
}

__global__ void scan_add_kernel(const int* __restrict__ bsums, int* __restrict__ rp, int n) {
  int i = blockIdx.x * 256 + threadIdx.x;
  if (i == 0) rp[0] = 0;
  if (i < n && blockIdx.x > 0) rp[i + 1] += bsums[blockIdx.x - 1];
}

__global__ void fill_all_kernel(const int* __restrict__ s0, const int* __restrict__ s1,
                                const int* __restrict__ s2, const int* __restrict__ s3,
                                const int* __restrict__ d0, const int* __restrict__ d1,
                                const int* __restrict__ d2, const int* __restrict__ d3,
                                const int* __restrict__ rp, int* __restrict__ fil,
                                int* __restrict__ csr) {
  int e = blockIdx.x * 256 + threadIdx.x;
  if (e >= E_N) return;
  int r = blockIdx.y;
  const int* ss = r == 0 ? s0 : r == 1 ? s1 : r == 2 ? s2 : s3;
  const int* ds = r == 0 ? d0 : r == 1 ? d1 : r == 2 ? d2 : d3;
  int ofs = r == 0 ? 0 : r == 1 ? NV_N : r == 2 ? (NV_N + NH_N) : (NV_N + NH_N + NE_N);
  int d = ofs + ds[e];
  int pos = rp[d] + atomicAdd(&fil[d], 1);
  csr[pos] = ss[e];
}

// ---------------- MFMA input projection (hi/lo, exact) ----------------
__global__ __launch_bounds__(256)
void proj_mfma_kernel(const float* __restrict__ x0, const float* __restrict__ x1,
                      const float* __restrict__ x2, const u16* __restrict__ Wp,
                      const float* __restrict__ bb0, const float* __restrict__ bb1,
                      const float* __restrict__ bb2,
                      u16* __restrict__ o0, u16* __restrict__ o1, u16* __restrict__ o2) {
  __shared__ u16 xs[64 * 32];  // 4KB
  int blk = blockIdx.x;
  const float* x; const float* bs; u16* o; int F, M, row0, t;
  if (blk < NBH)            { t = 0; x = x0; bs = bb0; o = o0; F = 16; M = NH_N; row0 = blk * 64; }
  else if (blk < NBH + NBV) { t = 1; x = x1; bs = bb1; o = o1; F = 10; M = NV_N; row0 = (blk - NBH) * 64; }
  else                      { t = 2; x = x2; bs = bb2; o = o2; F = 8;  M = NE_N; row0 = (blk - NBH - NBV) * 64; }
  const int tid = threadIdx.x;
  const int lane = tid & 63;
  const int w = tid >> 6;
  const int l15 = lane & 15;
  const int l4 = lane >> 4;

  *(uint4*)((char*)xs + tid * 16) = make_uint4(0, 0, 0, 0);
  __syncthreads();
  int total = 64 * F;
  for (int i = tid; i < total; i += 256) {
    int row = i / F, f = i % F;
    int gr = row0 + row; if (gr >= M) gr = M - 1;
    float v = x[(size_t)gr * F + f];
    u16 hi = f2bf(v);
    float lo = v - bf2f(hi);
    *(u16*)((char*)xs + ((row * 64 + f * 2) ^ ((row & 3) << 4))) = hi;
    *(u16*)((char*)xs + ((row * 64 + (f + 16) * 2) ^ ((row & 3) << 4))) = f2bf(lo);
  }
  __syncthreads();

  int arow = w * 16 + l15;
  short8v af = *(const short8v*)((const char*)xs + ((arow * 64 + l4 * 16) ^ ((arow & 3) << 4)));
  const u16* Wp_t = Wp + (size_t)t * 2 * 128 * 32;
  f32x4 acc[8];
  #pragma unroll
  for (int ni = 0; ni < 8; ++ni) {
    const u16* bp = Wp_t + (size_t)(ni * 16 + l15) * 32 + l4 * 8;
    short8v b1 = *(const short8v*)bp;
    short8v b2 = *(const short8v*)(bp + 128 * 32);
    f32x4 a0 = (f32x4){0.f, 0.f, 0.f, 0.f};
    a0 = __builtin_amdgcn_mfma_f32_16x16x32_bf16(af, b1, a0, 0, 0, 0);
    a0 = __builtin_amdgcn_mfma_f32_16x16x32_bf16(af, b2, a0, 0, 0, 0);
    acc[ni] = a0;
  }
  #pragma unroll
  for (int ni = 0; ni < 8; ++ni) {
    int col = ni * 16 + l15;
    float bv = bs[col];
    #pragma unroll
    for (int r = 0; r < 4; ++r) {
      int gr = row0 + w * 16 + l4 * 4 + r;
      if (gr >= M) continue;
      o[(size_t)gr * HD + col] = f2bf(fmaxf(acc[ni][r] + bv, 0.f));
    }
  }
}

// ---------------- gather-mean kernel (latency-optimized, no LDS, max occupancy) ----------------
__global__ __launch_bounds__(256)
void gather_layer_kernel(const u16* __restrict__ ch, const u16* __restrict__ cv,
                         const u16* __restrict__ ce, const int* __restrict__ csr,
                         const int* __restrict__ rp_hv, const int* __restrict__ rp_ev,
                         const int* __restrict__ rp_vh, const int* __restrict__ rp_ve,
                         u16* __restrict__ mv0, u16* __restrict__ mv1,
                         u16* __restrict__ mh, u16* __restrict__ me) {
  int blk = blockIdx.x;
  const u16* S; const int* rp; u16* mout; int M, row0;
  if (blk < GB_HV)                 { S = ch; rp = rp_hv; mout = mv0; M = NV_N; row0 = blk * 32; }
  else if (blk < GB_HV + GB_EV)    { S = ce; rp = rp_ev; mout = mv1; M = NV_N; row0 = (blk - GB_HV) * 32; }
  else if (blk < GB_HV + GB_EV + GB_VH) { S = cv; rp = rp_vh; mout = mh; M = NH_N; row0 = (blk - GB_HV - GB_EV) * 32; }
  else                             { S = cv; rp = rp_ve; mout = me; M = NE_N; row0 = (blk - GB_HV - GB_EV - GB_VH) * 32; }

  const int c8 = threadIdx.x & 7;
  const int gm = threadIdx.x >> 3;
  int ggr = row0 + gm; if (ggr >= M) ggr = M - 1;
  int s0 = rp[ggr], s1 = rp[ggr + 1];

  float fa[16];
  #pragma unroll
  for (int q = 0; q < 16; ++q) fa[q] = 0.f;

  int j = s0;
  for (; j + 3 < s1; j += 4) {
    int i0 = csr[j], i1 = csr[j + 1], i2 = csr[j + 2], i3 = csr[j + 3];
    const u16* p0 = S + (size_t)i0 * HD + c8 * 16;
    const u16* p1 = S + (size_t)i1 * HD + c8 * 16;
    const u16* p2 = S + (size_t)i2 * HD + c8 * 16;
    const u16* p3 = S + (size_t)i3 * HD + c8 * 16;
    short8v a0 = *(const short8v*)p0, a1 = *(const short8v*)(p0 + 8);
    short8v b0 = *(const short8v*)p1, b1 = *(const short8v*)(p1 + 8);
    short8v c0 = *(const short8v*)p2, c1 = *(const short8v*)(p2 + 8);
    short8v d0 = *(const short8v*)p3, d1 = *(const short8v*)(p3 + 8);
    #pragma unroll
    for (int q = 0; q < 8; ++q) {
      fa[q]     += (bf2f((u16)a0[q]) + bf2f((u16)b0[q])) + (bf2f((u16)c0[q]) + bf2f((u16)d0[q]));
      fa[8 + q] += (bf2f((u16)a1[q]) + bf2f((u16)b1[q])) + (bf2f((u16)c1[q]) + bf2f((u16)d1[q]));
    }
  }
  for (; j < s1; ++j) {
    const u16* p0 = S + (size_t)csr[j] * HD + c8 * 16;
    short8v a0 = *(const short8v*)p0, a1 = *(const short8v*)(p0 + 8);
    #pragma unroll
    for (int q = 0; q < 8; ++q) {
      fa[q] += bf2f((u16)a0[q]);
      fa[8 + q] += bf2f((u16)a1[q]);
    }
  }

  int cnt = s1 - s0; if (cnt < 1) cnt = 1;
  float inv = 1.f / (float)cnt;
  unsigned pw[8];
  #pragma unroll
  for (int q = 0; q < 8; ++q) {
    unsigned lo16 = f2bf(fa[2 * q] * inv);
    unsigned hi16 = f2bf(fa[2 * q + 1] * inv);
    pw[q] = lo16 | (hi16 << 16);
  }
  u16* wr_ = mout + (size_t)ggr * HD + c8 * 16;
  *(uint4*)wr_ = make_uint4(pw[0], pw[1], pw[2], pw[3]);
  *(uint4*)(wr_ + 8) = make_uint4(pw[4], pw[5], pw[6], pw[7]);
}

// ---------------- GEMM kernel: full-width tiles, W resident in LDS (conflict-free) -------
// Block = (type, 4 consecutive 64-row tiles), FULL 128 cols -> X staged ONCE per (tile,slot).
// W: bf16 hi-only, [kc16][n128][16B] per slot (linear copy in, conflict-free b128 reads).
extern __shared__ char smem[];
__global__ __launch_bounds__(256)
void gemm_layer_kernel(const u16* __restrict__ mv0, const u16* __restrict__ mv1,
                       const u16* __restrict__ mh, const u16* __restrict__ me,
                       const u16* __restrict__ cv, const u16* __restrict__ ch,
                       const u16* __restrict__ ce,
                       u16* __restrict__ nv, u16* __restrict__ nh, u16* __restrict__ ne,
                       const u16* __restrict__ Wt_l, const float* __restrict__ bcomb_l) {
  int blk = blockIdx.x;
  int type, t0;
  if (blk < BV)            { type = 0; t0 = blk * TPB; }
  else if (blk < BV + BH)  { type = 1; t0 = (blk - BV) * TPB; }
  else                     { type = 2; t0 = (blk - BV - BH) * TPB; }
  const int ntl = type == 0 ? TV : type == 1 ? TH : TE;
  int nt = ntl - t0; if (nt > TPB) nt = TPB;
  const int nslot = type == 0 ? 3 : 2;
  const int M = type == 0 ? NV_N : type == 1 ? NH_N : NE_N;
  const int mode = type == 0 ? 2 : 0;
  const u16* Xsrc[3];
  if (type == 0)      { Xsrc[0] = mv0; Xsrc[1] = mv1; Xsrc[2] = cv; }
  else if (type == 1) { Xsrc[0] = mh;  Xsrc[1] = ch;  Xsrc[2] = ch; }
  else                { Xsrc[0] = me;  Xsrc[1] = ce;  Xsrc[2] = ce; }
  const u16* Wg0 = Wt_l + (size_t)(type == 0 ? 0 : type == 1 ? 3 : 5) * WSLOT;
  u16* outp = type == 0 ? nv : type == 1 ? nh : ne;
  const float* bi = bcomb_l + (type == 0 ? 0 : type == 1 ? 128 : 256);

  const int tid = threadIdx.x;
  const int lane = tid & 63;
  const int w = tid >> 6;
  const int l15 = lane & 15;
  const int l4 = lane >> 4;
  const int mrow = w * 16 + l15;

  // ---- stage W (full 128 cols, hi only) into LDS: flat 32KB copy per slot ----
  for (int s = 0; s < nslot; ++s) {
    const u16* Wg = Wg0 + (size_t)s * WSLOT;
    char* wb = smem + s * 32768;
    for (int i = tid; i < 2048; i += 256) {
      uint4 v = *(const uint4*)(Wg + (size_t)i * 8);
      *(uint4*)(wb + i * 16) = v;
    }
  }
  char* xb = smem + 3 * 32768;

  for (int t = 0; t < nt; ++t) {
    int row0 = (t0 + t) * 64;
    f32x4 acc[8];
    #pragma unroll
    for (int ni = 0; ni < 8; ++ni) acc[ni] = (f32x4){0.f, 0.f, 0.f, 0.f};

    for (int s = 0; s < nslot; ++s) {
      __syncthreads();  // previous xb readers done (and W staged, at first entry)
      const u16* Xg = Xsrc[s];
      for (int i = tid; i < 1024; i += 256) {
        int m = i >> 4, cc = i & 15;
        int gr = row0 + m; if (gr >= M) gr = M - 1;
        uint4 v = *(const uint4*)(Xg + (size_t)gr * HD + cc * 8);
        *(uint4*)(xb + m * 256 + ((cc * 16) ^ ((m & 7) << 4))) = v;
      }
      __syncthreads();  // xb ready
      const char* wb = smem + s * 32768;
      #pragma unroll
      for (int kw = 0; kw < 4; ++kw) {
        int kb = kw * 64 + l4 * 16;
        short8v a = *(const short8v*)(xb + mrow * 256 + (kb ^ ((mrow & 7) << 4)));
        int kcw = kw * 4 + l4;
        #pragma unroll
        for (int ni = 0; ni < 8; ++ni) {
          const char* bp = wb + ((size_t)kcw * 128 + ni * 16 + l15) * 16;
          short8v bh_ = *(const short8v*)bp;
          acc[ni] = __builtin_amdgcn_mfma_f32_16x16x32_bf16(a, bh_, acc[ni], 0, 0, 0);
        }
      }
    }

    // epilogue: D col=lane&15 (+16*ni), row=(lane>>4)*4+r
    #pragma unroll
    for (int ni = 0; ni < 8; ++ni) {
      int col = ni * 16 + l15;
      float bv = bi[col];
      #pragma unroll
      for (int r = 0; r < 4; ++r) {
        int gr = row0 + w * 16 + l4 * 4 + r;
        if (gr >= M) continue;
        float v = acc[ni][r] + bv;
        v = (mode == 2) ? fmaxf(0.5f * v, 0.f) : fmaxf(v, 0.f);
        outp[(size_t)gr * HD + col] = f2bf(v);
      }
    }
  }
}

// ---------------- parallel batched mean pool ----------------
__global__ void pool_kernel(const u16* __restrict__ f0, const u16* __restrict__ f1,
                            const u16* __restrict__ f2, const int* __restrict__ seg,
                            float* __restrict__ pooled) {
  int t = blockIdx.z;
  const u16* hx = t == 0 ? f0 : t == 1 ? f1 : f2;
  int b = blockIdx.x, s = blockIdx.y, h = threadIdx.x;
  int lo = seg[t * 257 + b], hi = seg[t * 257 + b + 1];
  int len = hi - lo;
  int a0 = lo + (len * s) / PS, a1 = lo + (len * (s + 1)) / PS;
  float acc = 0.f;
  for (int i = a0; i < a1; ++i) acc += bf2f(hx[(size_t)i * HD + h]);
  if (a1 > a0) atomicAdd(&pooled[(size_t)b * 384 + t * 128 + h], acc);
}

// ---------------- final dense ----------------
__global__ void final_kernel(const float* __restrict__ pooled, const float* __restrict__ scalars,
                             const int* __restrict__ seg, const float* __restrict__ Wf,
                             const float* __restrict__ bf, float* __restrict__ out) {
  int b = blockIdx.x;
  int j = threadIdx.x;  // 128
  float iv[3];
  #pragma unroll
  for (int t = 0; t < 3; ++t) {
    int c = seg[t * 257 + b + 1] - seg[t * 257 + b];
    if (c < 1) c = 1;
    iv[t] = 1.f / (float)c;
  }
  float acc = bf[j];
  const float* pr = pooled + (size_t)b * 384;
  #pragma unroll
  for (int t = 0; t < 3; ++t)
    for (int k = 0; k < 128; ++k)
      acc = fmaf(pr[t * 128 + k] * iv[t], Wf[(size_t)(t * 128 + k) * 128 + j], acc);
  const float* sr = scalars + (size_t)b * NSCA;
  for (int s = 0; s < NSCA; ++s) acc = fmaf(sr[s], Wf[(size_t)(384 + s) * 128 + j], acc);
  out[(size_t)b * 128 + j] = acc;
}

extern "C" void kernel_launch(void* const* d_in, const int* in_sizes, int n_in,
                              void* d_out, int out_size, void* d_ws, size_t ws_size,
                              hipStream_t stream) {
  const float* x_hex   = (const float*)d_in[0];
  const float* x_vert  = (const float*)d_in[1];
  const float* x_edge  = (const float*)d_in[2];
  const float* scalars = (const float*)d_in[3];
  const int* src_hv = (const int*)d_in[4];
  const int* dst_hv = (const int*)d_in[5];
  const int* src_vh = (const int*)d_in[6];
  const int* dst_vh = (const int*)d_in[7];
  const int* src_ve = (const int*)d_in[8];
  const int* dst_ve = (const int*)d_in[9];
  const int* src_ev = (const int*)d_in[10];
  const int* dst_ev = (const int*)d_in[11];
  const int* batch_hex  = (const int*)d_in[12];
  const int* batch_vert = (const int*)d_in[13];
  const int* batch_edge = (const int*)d_in[14];
  const float* W_ph = (const float*)d_in[15];
  const float* b_ph = (const float*)d_in[16];
  const float* W_pv = (const float*)d_in[17];
  const float* b_pv = (const float*)d_in[18];
  const float* W_pe = (const float*)d_in[19];
  const float* b_pe = (const float*)d_in[20];
  const float* conv_Wl = (const float*)d_in[21];
  const float* conv_Wr = (const float*)d_in[22];
  const float* conv_b  = (const float*)d_in[23];
  const float* W_final = (const float*)d_in[24];
  const float* b_final = (const float*)d_in[25];
  float* out = (float*)d_out;

  // ---- workspace layout (~268 MB) ----
  char* wp = (char*)d_ws;
  size_t off = 0;
  auto alloc = [&](size_t bytes) -> void* {
    void* p = wp + off;
    off += (bytes + 511) & ~(size_t)511;
    return p;
  };
  u16* hbuf[2]; u16* vbuf[2]; u16* ebuf[2];
  hbuf[0] = (u16*)alloc((size_t)NH_N * HD * 2);
  hbuf[1] = (u16*)alloc((size_t)NH_N * HD * 2);
  vbuf[0] = (u16*)alloc((size_t)NV_N * HD * 2);
  vbuf[1] = (u16*)alloc((size_t)NV_N * HD * 2);
  ebuf[0] = (u16*)alloc((size_t)NE_N * HD * 2);
  ebuf[1] = (u16*)alloc((size_t)NE_N * HD * 2);
  u16* mv0 = (u16*)alloc((size_t)NV_N * HD * 2);
  u16* mv1 = (u16*)alloc((size_t)NV_N * HD * 2);
  u16* mh  = (u16*)alloc((size_t)NH_N * HD * 2);
  u16* me  = (u16*)alloc((size_t)NE_N * HD * 2);
  u16* Wt = (u16*)alloc((size_t)21 * WSLOT * 2);
  u16* Wp = (u16*)alloc((size_t)3 * 2 * 128 * 32 * 2);
  int* deg_all = (int*)alloc((size_t)800000 * 4);
  float* pooled = (float*)alloc((size_t)NBAT * 384 * 4);
  int* fil_all = deg_all + 400000;
  int* rp_all  = (int*)alloc((size_t)400001 * 4);
  int* csr_all = (int*)alloc((size_t)4 * E_N * 4);
  int* bsums   = (int*)alloc(2048 * 4);
  int* seg     = (int*)alloc(3 * 257 * 4);
  float* bcomb = (float*)alloc((size_t)NLAY * 3 * HD * 4);

  const int OFS_HV = 0;
  const int OFS_VH = NV_N;
  const int OFS_VE = NV_N + NH_N;
  const int OFS_EV = NV_N + NH_N + NE_N;
  const int NDEG = 400000;

  // ---- prep ----
  wprep_kernel<<<21, 256, 0, stream>>>(conv_Wl, conv_Wr, Wt);
  wprep_proj_kernel<<<3, 256, 0, stream>>>(W_ph, W_pv, W_pe, Wp);
  bias_prep_kernel<<<(NLAY * 3 * HD + 255) / 256, 256, 0, stream>>>(conv_b, bcomb);
  zero_kernel<<<(800000 + NBAT * 384 + 255) / 256, 256, 0, stream>>>(deg_all, 800000 + NBAT * 384);
  seg_kernel<<<1, 256, 0, stream>>>(batch_hex, batch_vert, batch_edge, seg);

  // ---- CSR build ----
  hist_all_kernel<<<dim3((E_N + 255) / 256, 4), 256, 0, stream>>>(dst_hv, dst_vh, dst_ve, dst_ev, deg_all);
  int nb = (NDEG + 255) / 256;
  scan_block_kernel<<<nb, 256, 0, stream>>>(deg_all, rp_all, bsums, NDEG);
  scan_sums_kernel<<<1, 256, 0, stream>>>(bsums, nb);
  scan_add_kernel<<<nb, 256, 0, stream>>>(bsums, rp_all, NDEG);
  fill_all_kernel<<<dim3((E_N + 255) / 256, 4), 256, 0, stream>>>(
      src_hv, src_vh, src_ve, src_ev, dst_hv, dst_vh, dst_ve, dst_ev, rp_all, fil_all, csr_all);

  // ---- input projections (MFMA) ----
  u16 *ch = hbuf[0], *cv = vbuf[0], *ce = ebuf[0];
  u16 *nh = hbuf[1], *nv = vbuf[1], *ne = ebuf[1];
  proj_mfma_kernel<<<NBH + NBV + NBE, 256, 0, stream>>>(
      x_hex, x_vert, x_edge, Wp, b_ph, b_pv, b_pe, ch, cv, ce);

  // ---- layers: gather (latency-regime) + GEMM (compute-regime) ----
  const int* rp_hv = rp_all + OFS_HV;
  const int* rp_vh = rp_all + OFS_VH;
  const int* rp_ve = rp_all + OFS_VE;
  const int* rp_ev = rp_all + OFS_EV;
  for (int l = 0; l < NLAY; ++l) {
    const u16* Wt_l = Wt + (size_t)(l * 7) * WSLOT;
    const float* bcomb_l = bcomb + (size_t)(l * 3) * HD;

    gather_layer_kernel<<<GB_TOT, 256, 0, stream>>>(
        ch, cv, ce, csr_all, rp_hv, rp_ev, rp_vh, rp_ve, mv0, mv1, mh, me);
    gemm_layer_kernel<<<GEMM_BLOCKS, 256, GEMM_LDS, stream>>>(
        mv0, mv1, mh, me, cv, ch, ce, nv, nh, ne, Wt_l, bcomb_l);

    u16* t;
    t = ch; ch = nh; nh = t;
    t = cv; cv = nv; nv = t;
    t = ce; ce = ne; ne = t;
  }

  // ---- pooling + final dense ----
  pool_kernel<<<dim3(NBAT, PS, 3), 128, 0, stream>>>(ch, cv, ce, seg, pooled);
  final_kernel<<<NBAT, 128, 0, stream>>>(pooled, scalars, seg, W_final, b_final, out);
}